// Round 1
// 2844.391 us; speedup vs baseline: 1.9492x; 1.9492x over previous
//
#include <hip/hip_runtime.h>
#include <hip/hip_bf16.h>

#define T_STEPS 256
#define BATCH   64
#define DIM_I   256
#define DIM_H   256
#define NBR     8
#define F_DIM   1024

typedef __attribute__((ext_vector_type(8))) short short8;
typedef __attribute__((ext_vector_type(4))) float floatx4;

// workspace layout (bytes)
#define WX_OFF  0u                  // 4 MB  bf16 W_x fragments [n][ks8][ct64][lane64][8]
#define WH_OFF  (4u<<20)            // 4 MB  bf16 W_h fragments [n][ks8][ct64][lane64][8]
#define C_OFF   (8u<<20)            // 512 KB fp32 c carry  [n][rt][tid512][8]
#define H_OFF   ((8u<<20) + 0x80000u) // 256 KB bf16 h carry [n][rt][row16][col256]
#define ZX_OFF  (16u<<20)           // CT * 2 MB fp32 z_x fragments [tt][n][rt][ct][lane][4]

__device__ __forceinline__ float sigmoid_fast(float x) {
    return 1.0f / (1.0f + __expf(-x));
}
__device__ __forceinline__ float tanh_fast(float x) {
    return 1.0f - 2.0f / (__expf(2.0f * x) + 1.0f);
}
// fp32 -> bf16 bits, round-to-nearest-even (finite inputs only)
__device__ __forceinline__ short f2bf(float f) {
    unsigned u = __float_as_uint(f);
    u += 0x7FFFu + ((u >> 16) & 1u);
    return (short)(u >> 16);
}

// ---------------------------------------------------------------------------
// Kernel 1: convert weight fp32 [N][512][1024] -> bf16 B-fragment order,
// split into W_x (k<256) and W_h (k>=256).
// Fragment layout: [n][ks][ct][lane][j], lane = qr*16 + c0, where for global k:
// ks=(k&255)>>5, qr=(k>>3)&3, j=k&7; ct=f>>4, c0=f&15.
// ---------------------------------------------------------------------------
__global__ void __launch_bounds__(256)
prep_kernel(const float* __restrict__ weight, short* __restrict__ wx,
            short* __restrict__ wh) {
    int id = blockIdx.x * 256 + threadIdx.x;     // 8*512*1024 = 4194304 total
    int f  = id & 1023;
    int kk = (id >> 10) & 511;
    int n  = id >> 19;
    float v = weight[(size_t)id];                // [n][kk][f] contiguous == id
    int ks = (kk & 255) >> 5;
    int qr = (kk >> 3) & 3;
    int j  = kk & 7;
    int ct = f >> 4;
    int c0 = f & 15;
    int lane = qr * 16 + c0;
    size_t o = ((((size_t)n * 8 + ks) * 64 + ct) * 64 + lane) * 8 + j;
    (kk < 256 ? wx : wh)[o] = f2bf(v);
}

// ---------------------------------------------------------------------------
// Kernel 2: z_x[tt][n][m][ct][lane][0..3] = x[t] @ W_x[n] + bias  (fp32, D-frag
// order). Grid CT*8 blocks (n = bid&7 for XCD locality of W_x[n]), 256 thr.
// Wave w covers coltiles w*16..w*16+15, all 4 row-subtiles (64 batch rows).
// ---------------------------------------------------------------------------
__global__ void __launch_bounds__(256)
xgemm_kernel(const float* __restrict__ x, const short* __restrict__ wxg,
             const float* __restrict__ bias_i, const float* __restrict__ bias_h,
             floatx4* __restrict__ zx, int t0) {
    const int tid = threadIdx.x;
    const int lane = tid & 63, w = tid >> 6;
    const int l15 = lane & 15, quad = lane >> 4;
    const int n = blockIdx.x & 7;
    const int tt = blockIdx.x >> 3;
    const int t = t0 + tt;

    const short8* wx8 = (const short8*)wxg + (size_t)n * 8 * 64 * 64;

    // A fragments: 4 row-subtiles x 8 k-steps, bf16 from fp32 x
    short8 a[4][8];
#pragma unroll
    for (int m = 0; m < 4; ++m) {
        const float* xr = x + ((size_t)t * BATCH + m * 16 + l15) * DIM_I + quad * 8;
#pragma unroll
        for (int ks = 0; ks < 8; ++ks) {
            const floatx4* p = (const floatx4*)(xr + ks * 32);
            floatx4 u = p[0], v = p[1];
            short8 af;
            af[0] = f2bf(u[0]); af[1] = f2bf(u[1]); af[2] = f2bf(u[2]); af[3] = f2bf(u[3]);
            af[4] = f2bf(v[0]); af[5] = f2bf(v[1]); af[6] = f2bf(v[2]); af[7] = f2bf(v[3]);
            a[m][ks] = af;
        }
    }

    for (int ci = 0; ci < 16; ++ci) {
        const int ct = w * 16 + ci;
        float bb = bias_i[n * F_DIM + ct * 16 + l15] + bias_h[n * F_DIM + ct * 16 + l15];
        short8 bw[8];
#pragma unroll
        for (int ks = 0; ks < 8; ++ks)
            bw[ks] = wx8[(ks * 64 + ct) * 64 + lane];
#pragma unroll
        for (int m = 0; m < 4; ++m) {
            floatx4 acc = (floatx4){bb, bb, bb, bb};
#pragma unroll
            for (int ks = 0; ks < 8; ++ks)
                acc = __builtin_amdgcn_mfma_f32_16x16x32_bf16(a[m][ks], bw[ks], acc, 0, 0, 0);
            zx[((((size_t)tt * 8 + n) * 4 + m) * 64 + ct) * 64 + lane] = acc;
        }
    }
}

// ---------------------------------------------------------------------------
// Kernel 3: recurrence. 32 blocks (n = bid&7 -> same-branch blocks share an
// XCD L2 copy of W_h[n]; rt = bid>>3 -> 16 batch rows). 512 threads = 8 waves;
// wave w owns h-cols w*32..w*32+31 (coltiles nt*16 + w*2 + q for all 4 gates,
// so the LSTM pointwise epilogue is lane-local). h ping-pongs in LDS (row pad
// +8 cols keeps ds_read_b128 bank-balanced). W_h ks{0,1} pinned in VGPRs,
// ks{2..7} streamed from L2 double-buffered. z_x prefetched one step ahead.
// NO inter-block communication: one __syncthreads per step.
// ---------------------------------------------------------------------------
__global__ void __launch_bounds__(512, 2)
rec_kernel(const floatx4* __restrict__ zx, const int* __restrict__ dur,
           const short* __restrict__ whg, float* __restrict__ out,
           float* __restrict__ c_carry, short* __restrict__ h_carry,
           int t0, int CT) {
    __shared__ short hlds[2][16 * 264];   // 2 x 8448 B, rows padded to 264 cols

    const int tid = threadIdx.x;
    const int lane = tid & 63, w = tid >> 6;
    const int l15 = lane & 15, quad = lane >> 4;
    const int n = blockIdx.x & 7;
    const int rt = blockIdx.x >> 3;
    const int r0 = rt * 16;

    const short8* wh8 = (const short8*)whg + (size_t)n * 8 * 64 * 64;

    // ---- load h carry into hlds[0] (zeroed by host at t=0) ----
    {
        const short8* src = (const short8*)(h_carry + ((size_t)n * 4 + rt) * 4096);
        int row = tid >> 5, cg = tid & 31;
        *(short8*)((char*)&hlds[0][0] + row * 528 + cg * 16) = src[tid];
    }
    // ---- load c carry ----
    float c[2][4];
    {
        const float* cp = c_carry + (((size_t)n * 4 + rt) * 512 + tid) * 8;
#pragma unroll
        for (int q = 0; q < 2; ++q)
#pragma unroll
            for (int r = 0; r < 4; ++r) c[q][r] = cp[q * 4 + r];
    }
    // ---- register-resident W_h for ks 0,1 (this wave's 8 coltiles) ----
    short8 wr0[8], wr1[8];
#pragma unroll
    for (int ci = 0; ci < 8; ++ci) {
        const int ct = (ci >> 1) * 16 + w * 2 + (ci & 1);
        wr0[ci] = wh8[(0 * 64 + ct) * 64 + lane];
        wr1[ci] = wh8[(1 * 64 + ct) * 64 + lane];
    }
    // ---- prefetch z_x for tt=0 ----
    floatx4 pf[8];
#pragma unroll
    for (int ci = 0; ci < 8; ++ci) {
        const int ct = (ci >> 1) * 16 + w * 2 + (ci & 1);
        pf[ci] = zx[(((size_t)0 * 8 + n) * 4 + rt) * 4096 + ct * 64 + lane];
    }
    __syncthreads();

    for (int tt = 0; tt < CT; ++tt) {
        const int t = t0 + tt;
        char* hc = (char*)&hlds[tt & 1][0];
        char* hn = (char*)&hlds[(tt + 1) & 1][0];

        // A fragments from LDS h (8 x ds_read_b128, bank-balanced via pad)
        short8 a[8];
#pragma unroll
        for (int ks = 0; ks < 8; ++ks)
            a[ks] = *(const short8*)(hc + l15 * 528 + ks * 64 + quad * 16);

        // accumulators start at z_x (bias + x-part already folded in)
        floatx4 acc[8];
#pragma unroll
        for (int ci = 0; ci < 8; ++ci) acc[ci] = pf[ci];

        int d4[4];
#pragma unroll
        for (int r = 0; r < 4; ++r)
            d4[r] = dur[(size_t)t * BATCH + r0 + quad * 4 + r];

        // prefetch next step's z_x (hidden under the MFMA loop)
        {
            const int ttn = (tt + 1 < CT) ? tt + 1 : tt;
#pragma unroll
            for (int ci = 0; ci < 8; ++ci) {
                const int ct = (ci >> 1) * 16 + w * 2 + (ci & 1);
                pf[ci] = zx[(((size_t)ttn * 8 + n) * 4 + rt) * 4096 + ct * 64 + lane];
            }
        }

        // stream ks 2..7 from L2, double-buffered one coltile ahead
        short8 sb[2][6];
#pragma unroll
        for (int ks = 0; ks < 6; ++ks)
            sb[0][ks] = wh8[((ks + 2) * 64 + (w * 2)) * 64 + lane];  // ci=0 -> ct=w*2

#pragma unroll
        for (int ci = 0; ci < 8; ++ci) {
            if (ci < 7) {
                const int ctn = ((ci + 1) >> 1) * 16 + w * 2 + ((ci + 1) & 1);
#pragma unroll
                for (int ks = 0; ks < 6; ++ks)
                    sb[(ci + 1) & 1][ks] = wh8[((ks + 2) * 64 + ctn) * 64 + lane];
            }
            acc[ci] = __builtin_amdgcn_mfma_f32_16x16x32_bf16(a[0], wr0[ci], acc[ci], 0, 0, 0);
            acc[ci] = __builtin_amdgcn_mfma_f32_16x16x32_bf16(a[1], wr1[ci], acc[ci], 0, 0, 0);
#pragma unroll
            for (int ks = 0; ks < 6; ++ks)
                acc[ci] = __builtin_amdgcn_mfma_f32_16x16x32_bf16(a[ks + 2], sb[ci & 1][ks], acc[ci], 0, 0, 0);
        }

        // ---- pointwise LSTM epilogue: lane-local ----
#pragma unroll
        for (int r = 0; r < 4; ++r) {
            const bool freeze = n > (d4[r] >> 3);
            const int row = quad * 4 + r;
#pragma unroll
            for (int q = 0; q < 2; ++q) {
                float zi = acc[0 + q][r];
                float zf = acc[2 + q][r];
                float zo = acc[4 + q][r];
                float zg = acc[6 + q][r];
                float ig = sigmoid_fast(zi);
                float fg = sigmoid_fast(zf);
                float og = sigmoid_fast(zo);
                float gg = tanh_fast(zg);
                float cn = freeze ? c[q][r] : fg * c[q][r] + ig * gg;
                c[q][r] = cn;
                float hv = og * tanh_fast(cn);
                const int hcol = w * 32 + q * 16 + l15;
                out[(((size_t)t * NBR + n) * BATCH + (r0 + row)) * DIM_H + hcol] = hv;
                *(short*)(hn + row * 528 + hcol * 2) = f2bf(hv);
            }
        }
        __syncthreads();   // h for step tt+1 ready (ping-pong buffer)
    }

    // ---- store carries for next chunk ----
    {
        float* cp = c_carry + (((size_t)n * 4 + rt) * 512 + tid) * 8;
#pragma unroll
        for (int q = 0; q < 2; ++q)
#pragma unroll
            for (int r = 0; r < 4; ++r) cp[q * 4 + r] = c[q][r];
        char* hf = (char*)&hlds[CT & 1][0];
        short8* dst = (short8*)(h_carry + ((size_t)n * 4 + rt) * 4096);
        int row = tid >> 5, cg = tid & 31;
        dst[tid] = *(const short8*)(hf + row * 528 + cg * 16);
    }
}

extern "C" void kernel_launch(void* const* d_in, const int* in_sizes, int n_in,
                              void* d_out, int out_size, void* d_ws, size_t ws_size,
                              hipStream_t stream) {
    const float* x      = (const float*)d_in[0];
    const int*   durp   = (const int*)d_in[1];
    const float* weight = (const float*)d_in[2];
    const float* bias_i = (const float*)d_in[3];
    const float* bias_h = (const float*)d_in[4];
    float* out = (float*)d_out;
    char*  ws  = (char*)d_ws;

    short*   wx      = (short*)(ws + WX_OFF);
    short*   wh      = (short*)(ws + WH_OFF);
    float*   c_carry = (float*)(ws + C_OFF);
    short*   h_carry = (short*)(ws + H_OFF);
    floatx4* zxp     = (floatx4*)(ws + ZX_OFF);

    // pick largest T-chunk whose z_x buffer fits the workspace (2 MB / step)
    int CT = 256;
    while (CT > 2 && (size_t)ZX_OFF + (size_t)CT * 2097152ull > ws_size) CT >>= 1;

    // zero h/c carries (t=0 state)
    hipMemsetAsync(ws + C_OFF, 0, 524288 + 262144, stream);

    // weight repack: fp32 -> bf16 fragments
    prep_kernel<<<16384, 256, 0, stream>>>(weight, wx, wh);

    for (int t0 = 0; t0 < T_STEPS; t0 += CT) {
        xgemm_kernel<<<CT * 8, 256, 0, stream>>>(x, wx, bias_i, bias_h, zxp, t0);
        rec_kernel<<<32, 512, 0, stream>>>(zxp, durp, wh, out, c_carry, h_carry, t0, CT);
    }
}